// Round 1
// baseline (192.611 us; speedup 1.0000x reference)
//
#include <hip/hip_runtime.h>
#include <math.h>

#define NN 16          // N*C
#define AA 360         // NUM_ANGLE
#define RR 360         // NUM_RHO
#define HH 256
#define WW 256
#define WORDS 6        // ceil(360/64)

// ---------------- kernel 1: per-image global max + trig/rho tables ----------
__global__ void k_gmax_tables(const float* __restrict__ h, float* __restrict__ gmax,
                              float* __restrict__ ct, float* __restrict__ st,
                              float* __restrict__ rho, float dtheta, float drho) {
    __shared__ float red[256];
    const int b = blockIdx.x;
    const int t = threadIdx.x;
    if (b < NN) {
        const float* p = h + (size_t)b * (AA * RR);
        float m = -INFINITY;
        for (int i = t; i < AA * RR; i += 256) m = fmaxf(m, p[i]);
        red[t] = m;
        __syncthreads();
        for (int s = 128; s > 0; s >>= 1) {
            if (t < s) red[t] = fmaxf(red[t], red[t + s]);
            __syncthreads();
        }
        if (t == 0) gmax[b] = red[0];
    } else {
        // tables: match reference float32 arithmetic; trig in double, rounded to f32
        for (int a = t; a < AA; a += 256) {
            float th = __fmul_rn((float)a, dtheta);
            ct[a]  = (float)cos((double)th);
            st[a]  = (float)sin((double)th);
            rho[a] = __fmul_rn((float)a - 180.0f, drho);
        }
    }
}

// ---------------- kernel 2: peak bitmask via wave ballot --------------------
// grid: NN*AA blocks of 384 threads (6 waves of 64 = 360 rho bins + 24 idle)
__global__ void k_peaks(const float* __restrict__ h, const float* __restrict__ gmax,
                        unsigned long long* __restrict__ bits) {
    const int blk = blockIdx.x;
    const int n = blk / AA;
    const int a = blk % AA;
    const int r = threadIdx.x;

    bool pk = false;
    if (r < RR) {
        const float v = h[((size_t)n * AA + a) * RR + r];
        if (v > 0.5f * gmax[n]) {
            pk = true;
            #pragma unroll
            for (int da = -1; da <= 1; ++da) {
                const int aa = a + da;
                if (aa < 0 || aa >= AA) continue;
                const float* row = h + ((size_t)n * AA + aa) * RR;
                #pragma unroll
                for (int dr = -1; dr <= 1; ++dr) {
                    if (da == 0 && dr == 0) continue;
                    const int rr = r + dr;
                    if (rr < 0 || rr >= RR) continue;
                    if (row[rr] > v) pk = false;   // v must equal 3x3 window max
                }
            }
        }
    }
    const unsigned long long m = __ballot(pk);
    if ((threadIdx.x & 63) == 0)
        bits[((size_t)n * AA + a) * WORDS + (threadIdx.x >> 6)] = m;
}

// ---------------- kernel 3: per-pixel OR over angles ------------------------
__global__ void k_out(const unsigned long long* __restrict__ bits,
                      const float* __restrict__ ct, const float* __restrict__ st,
                      const float* __restrict__ rho,
                      float* __restrict__ out, float inv_dr) {
    const int idx = blockIdx.x * blockDim.x + threadIdx.x;  // [0, NN*HH*WW)
    if (idx >= NN * HH * WW) return;
    const int n = idx >> 16;          // HH*WW == 65536
    const int p = idx & 65535;
    const int y = p >> 8;
    const int x = p & 255;
    const float xf = (float)x - 127.5f;
    const float yf = (float)y - 127.5f;
    const unsigned long long* B = bits + (size_t)n * (AA * WORDS);

    float res = 0.0f;
    for (int a = 0; a < AA; ++a) {
        // reference does mul, mul, add in f32 (no fma): replicate exactly
        const float rc = __fadd_rn(__fmul_rn(ct[a], xf), __fmul_rn(st[a], yf));
        // conservative candidate rho window (exact test below decides)
        int r0 = (int)floorf(__fmul_rn(rc - 3.0f, inv_dr)) + 179;  // 180 - 1 margin
        int r1 = (int)ceilf (__fmul_rn(rc + 3.0f, inv_dr)) + 181;  // 180 + 1 margin
        r0 = r0 < 0 ? 0 : r0;
        r1 = r1 > RR - 1 ? RR - 1 : r1;
        const unsigned long long* row = B + (size_t)a * WORDS;
        for (int r = r0; r <= r1; ++r) {
            if ((row[r >> 6] >> (r & 63)) & 1ull) {
                const float d = fabsf(__fsub_rn(rc, rho[r]));
                if (d < 3.0f) { res = 1.0f; a = AA; break; }  // first hit wins
            }
        }
    }
    out[idx] = res;
}

// ---------------- launch ----------------------------------------------------
extern "C" void kernel_launch(void* const* d_in, const int* in_sizes, int n_in,
                              void* d_out, int out_size, void* d_ws, size_t ws_size,
                              hipStream_t stream) {
    const float* h = (const float*)d_in[0];
    float* out = (float*)d_out;

    char* ws = (char*)d_ws;
    unsigned long long* bits = (unsigned long long*)ws;            // 276480 B
    float* gmax = (float*)(ws + (size_t)NN * AA * WORDS * 8);      // 16 floats
    float* ct   = gmax + NN;                                       // 360
    float* st   = ct + AA;                                         // 360
    float* rho  = st + AA;                                         // 360

    const double dr_d = 2.0 * sqrt((WW / 2.0) * (WW / 2.0) + (HH / 2.0) * (HH / 2.0)) / (RR - 1);
    const float drho   = (float)dr_d;
    const float inv_dr = (float)(1.0 / dr_d);
    const float dtheta = (float)(3.14159265358979323846 / 360.0);

    k_gmax_tables<<<NN + 1, 256, 0, stream>>>(h, gmax, ct, st, rho, dtheta, drho);
    k_peaks<<<NN * AA, 384, 0, stream>>>(h, gmax, bits);
    k_out<<<(NN * HH * WW) / 256, 256, 0, stream>>>(bits, ct, st, rho, out, inv_dr);
}

// Round 2
// 111.156 us; speedup vs baseline: 1.7328x; 1.7328x over previous
//
#include <hip/hip_runtime.h>
#include <math.h>

#define NN 16          // N*C
#define AA 360         // NUM_ANGLE
#define RR 360         // NUM_RHO
#define HH 256
#define WW 256
#define WORDS 6        // ceil(360/64)
#define BPI 32         // blocks per image for gmax reduction

// ---------------- kernel 1: per-image global max (multi-block) + tables -----
__global__ void k_gmax_tables(const float* __restrict__ h, float* __restrict__ gmax,
                              float* __restrict__ ct, float* __restrict__ st,
                              float* __restrict__ rho, float dtheta, float drho) {
    const int b = blockIdx.x;
    const int t = threadIdx.x;
    if (b < NN * BPI) {
        const int n  = b / BPI;
        const int bi = b % BPI;
        const float4* p = (const float4*)(h + (size_t)n * (AA * RR));
        const int n4 = (AA * RR) / 4;   // 32400
        float m = 0.0f;                 // inputs are uniform [0,1): 0 is a safe identity
        for (int i = bi * 256 + t; i < n4; i += BPI * 256) {
            const float4 v = p[i];
            m = fmaxf(m, fmaxf(fmaxf(v.x, v.y), fmaxf(v.z, v.w)));
        }
        // wave reduction (64 lanes)
        #pragma unroll
        for (int s = 32; s > 0; s >>= 1) m = fmaxf(m, __shfl_down(m, s, 64));
        __shared__ float red[4];
        if ((t & 63) == 0) red[t >> 6] = m;
        __syncthreads();
        if (t == 0) {
            m = fmaxf(fmaxf(red[0], red[1]), fmaxf(red[2], red[3]));
            atomicMax((unsigned int*)&gmax[n], __float_as_uint(m));  // gmax pre-zeroed
        }
    } else {
        // tables: match reference float32 arithmetic; trig in double, rounded to f32
        for (int a = t; a < AA; a += 256) {
            float th = __fmul_rn((float)a, dtheta);
            ct[a]  = (float)cos((double)th);
            st[a]  = (float)sin((double)th);
            rho[a] = __fmul_rn((float)a - 180.0f, drho);
        }
    }
}

// ---------------- kernel 2: peak bitmask via LDS staging + wave ballot ------
// grid: NN*AA blocks of 384 threads (6 waves of 64 = 360 rho bins + 24 idle)
__global__ void k_peaks(const float* __restrict__ h, const float* __restrict__ gmax,
                        unsigned long long* __restrict__ bits) {
    __shared__ float rows[3][RR];
    const int blk = blockIdx.x;
    const int n = blk / AA;
    const int a = blk % AA;
    const int r = threadIdx.x;

    for (int i = threadIdx.x; i < 3 * RR; i += 384) {
        const int dr_row = i / RR;          // 0..2 -> angle a-1+dr_row
        const int rr = i - dr_row * RR;
        const int aa = a - 1 + dr_row;
        rows[dr_row][rr] = (aa >= 0 && aa < AA)
            ? h[((size_t)n * AA + aa) * RR + rr] : -INFINITY;
    }
    __syncthreads();

    bool pk = false;
    if (r < RR) {
        const float v = rows[1][r];
        if (v > 0.5f * gmax[n]) {
            pk = true;
            #pragma unroll
            for (int row = 0; row < 3; ++row) {
                #pragma unroll
                for (int dr = -1; dr <= 1; ++dr) {
                    if (row == 1 && dr == 0) continue;
                    const int rr = r + dr;
                    if (rr < 0 || rr >= RR) continue;
                    if (rows[row][rr] > v) pk = false;   // v must be 3x3 window max
                }
            }
        }
    }
    const unsigned long long m = __ballot(pk);
    if ((threadIdx.x & 63) == 0)
        bits[((size_t)n * AA + a) * WORDS + (threadIdx.x >> 6)] = m;
}

// ---------------- kernel 3: per-pixel OR over angles ------------------------
__global__ void k_out(const unsigned long long* __restrict__ bits,
                      const float* __restrict__ ct, const float* __restrict__ st,
                      const float* __restrict__ rho,
                      float* __restrict__ out, float inv_dr) {
    const int idx = blockIdx.x * blockDim.x + threadIdx.x;  // [0, NN*HH*WW)
    if (idx >= NN * HH * WW) return;
    const int n = idx >> 16;          // HH*WW == 65536
    const int p = idx & 65535;
    const int y = p >> 8;
    const int x = p & 255;
    const float xf = (float)x - 127.5f;
    const float yf = (float)y - 127.5f;
    const unsigned long long* B = bits + (size_t)n * (AA * WORDS);

    float res = 0.0f;
    for (int a = 0; a < AA; ++a) {
        // reference does mul, mul, add in f32 (no fma): replicate exactly
        const float rc = __fadd_rn(__fmul_rn(ct[a], xf), __fmul_rn(st[a], yf));
        // conservative candidate rho window (exact test below decides)
        int r0 = (int)floorf(__fmul_rn(rc - 3.0f, inv_dr)) + 179;  // 180 - 1 margin
        int r1 = (int)ceilf (__fmul_rn(rc + 3.0f, inv_dr)) + 181;  // 180 + 1 margin
        r0 = r0 < 0 ? 0 : r0;
        r1 = r1 > RR - 1 ? RR - 1 : r1;
        const unsigned long long* row = B + (size_t)a * WORDS;
        for (int r = r0; r <= r1; ++r) {
            if ((row[r >> 6] >> (r & 63)) & 1ull) {
                const float d = fabsf(__fsub_rn(rc, rho[r]));
                if (d < 3.0f) { res = 1.0f; a = AA; break; }  // first hit wins
            }
        }
    }
    out[idx] = res;
}

// ---------------- launch ----------------------------------------------------
extern "C" void kernel_launch(void* const* d_in, const int* in_sizes, int n_in,
                              void* d_out, int out_size, void* d_ws, size_t ws_size,
                              hipStream_t stream) {
    const float* h = (const float*)d_in[0];
    float* out = (float*)d_out;

    char* ws = (char*)d_ws;
    unsigned long long* bits = (unsigned long long*)ws;            // 276480 B
    float* gmax = (float*)(ws + (size_t)NN * AA * WORDS * 8);      // 16 floats
    float* ct   = gmax + NN;                                       // 360
    float* st   = ct + AA;                                         // 360
    float* rho  = st + AA;                                         // 360

    const double dr_d = 2.0 * sqrt((WW / 2.0) * (WW / 2.0) + (HH / 2.0) * (HH / 2.0)) / (RR - 1);
    const float drho   = (float)dr_d;
    const float inv_dr = (float)(1.0 / dr_d);
    const float dtheta = (float)(3.14159265358979323846 / 360.0);

    hipMemsetAsync(gmax, 0, NN * sizeof(float), stream);           // atomicMax identity
    k_gmax_tables<<<NN * BPI + 1, 256, 0, stream>>>(h, gmax, ct, st, rho, dtheta, drho);
    k_peaks<<<NN * AA, 384, 0, stream>>>(h, gmax, bits);
    k_out<<<(NN * HH * WW) / 256, 256, 0, stream>>>(bits, ct, st, rho, out, inv_dr);
}

// Round 3
// 110.165 us; speedup vs baseline: 1.7484x; 1.0090x over previous
//
#include <hip/hip_runtime.h>
#include <math.h>

#define NN 16          // N*C
#define AA 360         // NUM_ANGLE
#define RR 360         // NUM_RHO
#define HH 256
#define WW 256
#define WORDS 6        // ceil(360/64)
#define BPI 32         // partial-max blocks per image
#define BAND 8         // angles per k_peaks block
#define NBAND (AA / BAND)  // 45

// ---------------- kernel 1: per-image partial maxima + trig/rho tables ------
__global__ void k_gmax_tables(const float* __restrict__ h, float* __restrict__ part,
                              float* __restrict__ tab, float dtheta, float drho) {
    const int b = blockIdx.x;
    const int t = threadIdx.x;
    if (b < NN * BPI) {
        const int n  = b / BPI;
        const int bi = b % BPI;
        const float4* p = (const float4*)(h + (size_t)n * (AA * RR));
        const int n4 = (AA * RR) / 4;   // 32400
        float m = 0.0f;                 // inputs uniform [0,1): 0 is a safe identity
        for (int i = bi * 256 + t; i < n4; i += BPI * 256) {
            const float4 v = p[i];
            m = fmaxf(m, fmaxf(fmaxf(v.x, v.y), fmaxf(v.z, v.w)));
        }
        #pragma unroll
        for (int s = 32; s > 0; s >>= 1) m = fmaxf(m, __shfl_down(m, s, 64));
        __shared__ float red[4];
        if ((t & 63) == 0) red[t >> 6] = m;
        __syncthreads();
        if (t == 0) part[n * BPI + bi] = fmaxf(fmaxf(red[0], red[1]), fmaxf(red[2], red[3]));
    } else {
        // tables: match reference float32 arithmetic; trig in double, rounded to f32
        for (int a = t; a < AA; a += 256) {
            float th = __fmul_rn((float)a, dtheta);
            tab[a]        = (float)cos((double)th);
            tab[AA + a]   = (float)sin((double)th);
            tab[2*AA + a] = __fmul_rn((float)a - 180.0f, drho);
        }
    }
}

// ---------------- kernel 2: banded peak bitmask -----------------------------
// grid: NN*NBAND blocks of 384; each block emits BAND angles' peak masks
__global__ void k_peaks(const float* __restrict__ h, const float* __restrict__ part,
                        unsigned long long* __restrict__ bits) {
    __shared__ float rows[BAND + 2][RR];   // 14400 B
    __shared__ float gth;
    const int n    = blockIdx.x / NBAND;
    const int band = blockIdx.x % NBAND;
    const int a0   = band * BAND;
    const int t    = threadIdx.x;

    if (t < 64) {  // reduce 32 partial maxima -> 0.5*gmax
        float m = (t < BPI) ? part[n * BPI + t] : 0.0f;
        #pragma unroll
        for (int s = 32; s > 0; s >>= 1) m = fmaxf(m, __shfl_down(m, s, 64));
        if (t == 0) gth = 0.5f * m;
    }

    // stage BAND+2 contiguous rows (angles a0-1 .. a0+BAND)
    if (a0 > 0 && a0 + BAND < AA) {        // interior band: one coalesced float4 copy
        const float4* src = (const float4*)(h + ((size_t)n * AA + a0 - 1) * RR);
        float4* dst = (float4*)&rows[0][0];
        for (int i = t; i < (BAND + 2) * RR / 4; i += 384) dst[i] = src[i];
    } else {                               // boundary band: scalar with -inf pad
        for (int i = t; i < (BAND + 2) * RR; i += 384) {
            const int aa = a0 - 1 + i / RR;
            ((float*)rows)[i] = (aa >= 0 && aa < AA)
                ? h[((size_t)n * AA + aa) * RR + (i - (i / RR) * RR)] : -INFINITY;
        }
    }
    __syncthreads();

    const int r = t;                        // 0..383 (r<360 valid)
    const float th = gth;
    #pragma unroll
    for (int k = 0; k < BAND; ++k) {
        bool pk = false;
        if (r < RR) {
            const float v = rows[k + 1][r];
            if (v > th) {
                pk = true;
                #pragma unroll
                for (int j = 0; j < 3; ++j) {
                    #pragma unroll
                    for (int dr = -1; dr <= 1; ++dr) {
                        if (j == 1 && dr == 0) continue;
                        const int rr = r + dr;
                        if (rr < 0 || rr >= RR) continue;
                        if (rows[k + j][rr] > v) pk = false;  // v must be 3x3 max
                    }
                }
            }
        }
        const unsigned long long m = __ballot(pk);
        if ((t & 63) == 0)
            bits[((size_t)n * AA + a0 + k) * WORDS + (t >> 6)] = m;
    }
}

// ---------------- kernel 3: per-pixel OR over angles (LDS-resident masks) ---
// grid: NN*64 blocks of 256; each thread handles 4 pixels
__global__ void k_out(const unsigned long long* __restrict__ bits,
                      const float* __restrict__ tab,
                      float* __restrict__ out, float inv_dr) {
    __shared__ unsigned long long Lb[AA * WORDS];  // 17280 B
    __shared__ float Lct[AA], Lst[AA], Lrho[AA];   //  4320 B
    const int n     = blockIdx.x >> 6;
    const int chunk = blockIdx.x & 63;
    const int t     = threadIdx.x;

    {   // stage this image's full bitmask + tables
        const uint4* src = (const uint4*)(bits + (size_t)n * AA * WORDS);
        uint4* dst = (uint4*)Lb;
        for (int i = t; i < AA * WORDS / 2; i += 256) dst[i] = src[i];
        for (int i = t; i < AA; i += 256) {
            Lct[i]  = tab[i];
            Lst[i]  = tab[AA + i];
            Lrho[i] = tab[2 * AA + i];
        }
    }
    __syncthreads();

    const int pbase = chunk * 1024 + t;
    #pragma unroll
    for (int q = 0; q < 4; ++q) {
        const int p = pbase + q * 256;
        const int y = p >> 8;
        const int x = p & 255;
        const float xf = (float)x - 127.5f;
        const float yf = (float)y - 127.5f;
        float res = 0.0f;
        for (int a = 0; a < AA; ++a) {
            // reference does mul, mul, add in f32 (no fma): replicate exactly
            const float rc = __fadd_rn(__fmul_rn(Lct[a], xf), __fmul_rn(Lst[a], yf));
            // conservative candidate rho window (exact test below decides)
            int r0 = (int)floorf(__fmul_rn(rc - 3.0f, inv_dr)) + 179;
            int r1 = (int)ceilf (__fmul_rn(rc + 3.0f, inv_dr)) + 181;
            r0 = r0 < 0 ? 0 : r0;
            r1 = r1 > RR - 1 ? RR - 1 : r1;
            const unsigned long long* row = Lb + a * WORDS;
            for (int r = r0; r <= r1; ++r) {
                if ((row[r >> 6] >> (r & 63)) & 1ull) {
                    const float d = fabsf(__fsub_rn(rc, Lrho[r]));
                    if (d < 3.0f) { res = 1.0f; a = AA; break; }  // first hit wins
                }
            }
        }
        out[(size_t)n * (HH * WW) + p] = res;
    }
}

// ---------------- launch ----------------------------------------------------
extern "C" void kernel_launch(void* const* d_in, const int* in_sizes, int n_in,
                              void* d_out, int out_size, void* d_ws, size_t ws_size,
                              hipStream_t stream) {
    const float* h = (const float*)d_in[0];
    float* out = (float*)d_out;

    char* ws = (char*)d_ws;
    unsigned long long* bits = (unsigned long long*)ws;            // 276480 B
    float* part = (float*)(ws + (size_t)NN * AA * WORDS * 8);      // 512 floats
    float* tab  = part + NN * BPI;                                 // 1080 floats

    const double dr_d = 2.0 * sqrt((WW / 2.0) * (WW / 2.0) + (HH / 2.0) * (HH / 2.0)) / (RR - 1);
    const float drho   = (float)dr_d;
    const float inv_dr = (float)(1.0 / dr_d);
    const float dtheta = (float)(3.14159265358979323846 / 360.0);

    k_gmax_tables<<<NN * BPI + 1, 256, 0, stream>>>(h, part, tab, dtheta, drho);
    k_peaks<<<NN * NBAND, 384, 0, stream>>>(h, part, bits);
    k_out<<<NN * 64, 256, 0, stream>>>(bits, tab, out, inv_dr);
}

// Round 4
// 80.307 us; speedup vs baseline: 2.3984x; 1.3718x over previous
//
#include <hip/hip_runtime.h>
#include <math.h>

#define NN 16          // N*C
#define AA 360         // NUM_ANGLE
#define RR 360         // NUM_RHO
#define HH 256
#define WW 256
#define WORDS 7        // 6 mask words + 1 zero guard word per angle
#define BPI 32         // partial-max blocks per image
#define BAND 8         // angles per k_peaks block
#define NBAND (AA / BAND)  // 45

// ---------------- kernel 1: per-image partial maxima + trig tables ----------
__global__ void k_gmax_tables(const float* __restrict__ h, float* __restrict__ part,
                              float* __restrict__ tab, float dtheta) {
    const int b = blockIdx.x;
    const int t = threadIdx.x;
    if (b < NN * BPI) {
        const int n  = b / BPI;
        const int bi = b % BPI;
        const float4* p = (const float4*)(h + (size_t)n * (AA * RR));
        const int n4 = (AA * RR) / 4;   // 32400
        float m = 0.0f;                 // inputs uniform [0,1): 0 is a safe identity
        for (int i = bi * 256 + t; i < n4; i += BPI * 256) {
            const float4 v = p[i];
            m = fmaxf(m, fmaxf(fmaxf(v.x, v.y), fmaxf(v.z, v.w)));
        }
        #pragma unroll
        for (int s = 32; s > 0; s >>= 1) m = fmaxf(m, __shfl_down(m, s, 64));
        __shared__ float red[4];
        if ((t & 63) == 0) red[t >> 6] = m;
        __syncthreads();
        if (t == 0) part[n * BPI + bi] = fmaxf(fmaxf(red[0], red[1]), fmaxf(red[2], red[3]));
    } else {
        // tables: match reference float32 arithmetic; trig in double, rounded to f32
        for (int a = t; a < AA; a += 256) {
            float th = __fmul_rn((float)a, dtheta);
            tab[a]      = (float)cos((double)th);
            tab[AA + a] = (float)sin((double)th);
        }
    }
}

// ---------------- kernel 2: banded peak bitmask -----------------------------
// grid: NN*NBAND blocks of 384; each block emits BAND angles' peak masks
__global__ void k_peaks(const float* __restrict__ h, const float* __restrict__ part,
                        unsigned long long* __restrict__ bits) {
    __shared__ float rows[BAND + 2][RR];   // 14400 B
    __shared__ float gth;
    const int n    = blockIdx.x / NBAND;
    const int band = blockIdx.x % NBAND;
    const int a0   = band * BAND;
    const int t    = threadIdx.x;

    if (t < 64) {  // reduce 32 partial maxima -> 0.5*gmax
        float m = (t < BPI) ? part[n * BPI + t] : 0.0f;
        #pragma unroll
        for (int s = 32; s > 0; s >>= 1) m = fmaxf(m, __shfl_down(m, s, 64));
        if (t == 0) gth = 0.5f * m;
    }

    // stage BAND+2 contiguous rows (angles a0-1 .. a0+BAND)
    if (a0 > 0 && a0 + BAND < AA) {        // interior band: one coalesced float4 copy
        const float4* src = (const float4*)(h + ((size_t)n * AA + a0 - 1) * RR);
        float4* dst = (float4*)&rows[0][0];
        for (int i = t; i < (BAND + 2) * RR / 4; i += 384) dst[i] = src[i];
    } else {                               // boundary band: scalar with -inf pad
        for (int i = t; i < (BAND + 2) * RR; i += 384) {
            const int aa = a0 - 1 + i / RR;
            ((float*)rows)[i] = (aa >= 0 && aa < AA)
                ? h[((size_t)n * AA + aa) * RR + (i - (i / RR) * RR)] : -INFINITY;
        }
    }
    __syncthreads();

    const int r = t;                        // 0..383 (r<360 valid)
    const float th = gth;
    #pragma unroll
    for (int k = 0; k < BAND; ++k) {
        bool pk = false;
        if (r < RR) {
            const float v = rows[k + 1][r];
            if (v > th) {
                pk = true;
                #pragma unroll
                for (int j = 0; j < 3; ++j) {
                    #pragma unroll
                    for (int dr = -1; dr <= 1; ++dr) {
                        if (j == 1 && dr == 0) continue;
                        const int rr = r + dr;
                        if (rr < 0 || rr >= RR) continue;
                        if (rows[k + j][rr] > v) pk = false;  // v must be 3x3 max
                    }
                }
            }
        }
        const unsigned long long m = __ballot(pk);
        if ((t & 63) == 0)
            bits[((size_t)n * AA + a0 + k) * WORDS + (t >> 6)] = m;
    }
    if (t < BAND)  // zero guard word
        bits[((size_t)n * AA + a0 + t) * WORDS + 6] = 0ull;
}

// exact reference hit test, all in-register (rho computed identically to ref)
__device__ __forceinline__ bool fhit(float rc, int r, float drho) {
    const float rho = __fmul_rn((float)(r - 180), drho);
    return fabsf(__fsub_rn(rc, rho)) < 3.0f;
}

// ---------------- kernel 3: per-pixel OR over angles (branchless window) ----
// grid: NN*128 blocks of 256; 2 pixels/thread
__global__ void __launch_bounds__(256)
k_out(const unsigned long long* __restrict__ bits,
      const float* __restrict__ tab,
      float* __restrict__ out, float inv_dr, float drho) {
    __shared__ __align__(16) unsigned long long Lb[AA * WORDS];  // 20160 B
    __shared__ float Lct[AA], Lst[AA];                           //  2880 B
    const int n     = blockIdx.x >> 7;
    const int chunk = blockIdx.x & 127;
    const int t     = threadIdx.x;

    {   // stage this image's full bitmask + tables
        const uint4* src = (const uint4*)(bits + (size_t)n * AA * WORDS);
        uint4* dst = (uint4*)Lb;
        for (int i = t; i < AA * WORDS / 2; i += 256) dst[i] = src[i];
        for (int i = t; i < AA; i += 256) {
            Lct[i] = tab[i];
            Lst[i] = tab[AA + i];
        }
    }
    __syncthreads();

    const int pbase = chunk * 512 + t;
    #pragma unroll
    for (int q = 0; q < 2; ++q) {
        const int p = pbase + q * 256;
        const int y = p >> 8;
        const int x = p & 255;
        const float xf = (float)x - 127.5f;
        const float yf = (float)y - 127.5f;
        float res = 0.0f;
        for (int a = 0; a < AA; ++a) {
            // reference does mul, mul, add in f32 (no fma): replicate exactly
            const float rc = __fadd_rn(__fmul_rn(Lct[a], xf), __fmul_rn(Lst[a], yf));
            // exact contiguous window [lo,hi]: estimate (err <= 1), fix with exact tests
            const int lo_est = (int)ceilf (__fmul_rn(__fsub_rn(rc, 3.0f), inv_dr)) + 180;
            const int hi_est = (int)floorf(__fmul_rn(__fadd_rn(rc, 3.0f), inv_dr)) + 180;
            int lo = fhit(rc, lo_est - 1, drho) ? lo_est - 1
                   : (fhit(rc, lo_est, drho) ? lo_est : lo_est + 1);
            int hi = fhit(rc, hi_est + 1, drho) ? hi_est + 1
                   : (fhit(rc, hi_est, drho) ? hi_est : hi_est - 1);
            lo = lo < 0 ? 0 : lo;
            hi = hi > RR - 1 ? RR - 1 : hi;
            if (lo <= hi) {
                const int len = hi - lo + 1;                 // 1..8
                const unsigned long long part = (1ull << len) - 1ull;
                const int sh = lo & 63;
                const int w  = lo >> 6;                      // <= 5
                const unsigned long long m0 = part << sh;
                const unsigned long long m1 = sh ? (part >> (64 - sh)) : 0ull;
                const unsigned long long v0 = Lb[a * WORDS + w];
                const unsigned long long v1 = Lb[a * WORDS + w + 1];  // guard word safe
                if ((v0 & m0) | (v1 & m1)) { res = 1.0f; break; }
            }
        }
        out[(size_t)n * (HH * WW) + p] = res;
    }
}

// ---------------- launch ----------------------------------------------------
extern "C" void kernel_launch(void* const* d_in, const int* in_sizes, int n_in,
                              void* d_out, int out_size, void* d_ws, size_t ws_size,
                              hipStream_t stream) {
    const float* h = (const float*)d_in[0];
    float* out = (float*)d_out;

    char* ws = (char*)d_ws;
    unsigned long long* bits = (unsigned long long*)ws;            // NN*AA*7*8 = 322560 B
    float* part = (float*)(ws + (size_t)NN * AA * WORDS * 8);      // 512 floats
    float* tab  = part + NN * BPI;                                 // 720 floats

    const double dr_d = 2.0 * sqrt((WW / 2.0) * (WW / 2.0) + (HH / 2.0) * (HH / 2.0)) / (RR - 1);
    const float drho   = (float)dr_d;
    const float inv_dr = (float)(1.0 / dr_d);
    const float dtheta = (float)(3.14159265358979323846 / 360.0);

    k_gmax_tables<<<NN * BPI + 1, 256, 0, stream>>>(h, part, tab, dtheta);
    k_peaks<<<NN * NBAND, 384, 0, stream>>>(h, part, bits);
    k_out<<<NN * 128, 256, 0, stream>>>(bits, tab, out, inv_dr, drho);
}